// Round 1
// baseline (1875.020 us; speedup 1.0000x reference)
//
#include <hip/hip_runtime.h>
#include <hip/hip_fp16.h>
#include <hip/hip_cooperative_groups.h>

namespace cg = cooperative_groups;

// Problem constants
#define NB   64     // batch
#define NDEC 12     // decoder steps
#define NF   32     // input features
#define NH   512    // hidden
#define NE   96     // encoder length
#define NT   4      // output dim

typedef _Float16 half8_t __attribute__((ext_vector_type(8)));
typedef float   float4_t __attribute__((ext_vector_type(4)));

__device__ __forceinline__ float fast_tanh(float x) {
    x = fminf(fmaxf(x, -15.f), 15.f);
    float e = __expf(2.f * x);
    return (e - 1.f) / (e + 1.f);
}
__device__ __forceinline__ float fast_sig(float x) {
    return 1.f / (1.f + __expf(-x));
}

// ---------------------------------------------------------------------------
// One-time: fp32->fp16 weight converts (+ Wa_h transpose, Wa_e fp16) + state init.
__global__ __launch_bounds__(256) void k_prep(
    const float* __restrict__ Wi0, const float* __restrict__ Wh0,
    const float* __restrict__ Wi1, const float* __restrict__ Wh1,
    const float* __restrict__ Wout, const float* __restrict__ Wattn,
    const float* __restrict__ hidden, const float* __restrict__ inputs,
    __half* __restrict__ Wi0h, __half* __restrict__ Wh0h,
    __half* __restrict__ Wi1h, __half* __restrict__ Wh1h,
    __half* __restrict__ Wouth, __half* __restrict__ WahT,
    __half* __restrict__ WaeH,
    float* __restrict__ h0c, float* __restrict__ h1c,
    float* __restrict__ h1row, float* __restrict__ curc)
{
    int i = blockIdx.x*256 + threadIdx.x;
    const int n0 = 1536*544, n1 = 1536*512, n4 = 4*1056, n5 = 512*512;
    if (i < n0) { Wi0h[i] = __float2half_rn(Wi0[i]); return; }  i -= n0;
    if (i < n1) { Wh0h[i] = __float2half_rn(Wh0[i]); return; }  i -= n1;
    if (i < n1) { Wi1h[i] = __float2half_rn(Wi1[i]); return; }  i -= n1;
    if (i < n1) { Wh1h[i] = __float2half_rn(Wh1[i]); return; }  i -= n1;
    if (i < n4) { Wouth[i] = __float2half_rn(Wout[i]); return; } i -= n4;
    if (i < n5) {
        int k = i >> 9, g = i & 511;                 // WahT[k][g] = Wattn[g][k]
        WahT[i] = __float2half_rn(Wattn[(size_t)g*1024 + k]);
        return;
    }
    i -= n5;
    if (i < n5) {                                     // WaeH[g][k] = Wattn[g][512+k]
        int g = i >> 9, k = i & 511;
        WaeH[i] = __float2half_rn(Wattn[(size_t)g*1024 + 512 + k]);
        return;
    }
    i -= n5;
    if (i < NB*NH) {                                  // state init
        int b = i >> 9, k = i & 511;
        float v0 = hidden[b*NH + k];
        float v1 = hidden[NB*NH + b*NH + k];
        h0c[k*NB + b] = v0;
        h1c[k*NB + b] = v1;
        h1row[b*NH + k] = v1;
        return;
    }
    i -= NB*NH;
    if (i < NB*NF) {                                  // cur(0)
        int b = i >> 5, k = i & 31;
        curc[k*NB + b] = inputs[b*NDEC*NF + k];
    }
}

// ---------------------------------------------------------------------------
// enc_proj via MFMA f16: encp[be][g] = sum_k enc[be][k] * WaeH[g][k].
__global__ __launch_bounds__(256) void k_encproj(const float* __restrict__ enc,
                                                 const __half* __restrict__ WaeH,
                                                 __half* __restrict__ encph) {
    int x = blockIdx.x;                 // 768 = 96 (m-tiles) x 8 (n-tiles)
    int by = x >> 3, bx = x & 7;
    int t = threadIdx.x, w = t >> 6, lane = t & 63;
    int mr = lane & 15, kq = lane >> 4;          // kq in 0..3
    int m = by*64 + w*16 + mr;
    const float* arow = enc + (size_t)m*NH;
    float4_t acc[4] = {{0.f,0.f,0.f,0.f},{0.f,0.f,0.f,0.f},
                       {0.f,0.f,0.f,0.f},{0.f,0.f,0.f,0.f}};
    for (int kb = 0; kb < NH; kb += 32) {
        int k = kb + kq*8;
        float4 a0 = *(const float4*)(arow + k);
        float4 a1 = *(const float4*)(arow + k + 4);
        half8_t a;
        a[0] = (_Float16)a0.x; a[1] = (_Float16)a0.y;
        a[2] = (_Float16)a0.z; a[3] = (_Float16)a0.w;
        a[4] = (_Float16)a1.x; a[5] = (_Float16)a1.y;
        a[6] = (_Float16)a1.z; a[7] = (_Float16)a1.w;
        #pragma unroll
        for (int j = 0; j < 4; ++j) {
            int n = bx*64 + j*16 + mr;
            half8_t b = *(const half8_t*)(WaeH + (size_t)n*NH + k);
            acc[j] = __builtin_amdgcn_mfma_f32_16x16x32_f16(a, b, acc[j], 0, 0, 0);
        }
    }
    #pragma unroll
    for (int j = 0; j < 4; ++j) {
        int col = bx*64 + j*16 + mr;
        #pragma unroll
        for (int r = 0; r < 4; ++r) {
            int row = by*64 + w*16 + kq*4 + r;
            encph[(size_t)row*NH + col] = __float2half_rn(acc[j][r]);
        }
    }
}

// ---------------------------------------------------------------------------
// Fused whole-decode-loop cooperative kernel. Grid = 160 x 1024.
//  Per step: phase A (blocks 0..63 att path; 64..159 ghb recurrent-half GEMV)
//            grid.sync
//            phase B (gru layer 0) grid.sync
//            phase C (gru layer 1) grid.sync
//  Bodies are verbatim copies of the previous k_step / k_gru kernels
//  (same FP order => identical numerics); only launch structure changed.
struct LoopArgs {
    const float* inputs; const int* tgt;
    const __half* WahT; const float* battn; const float* vattn;
    const __half* Wouth; const float* bout;
    const __half* encph; const float* enc;
    const __half* Wh0h; const __half* Wh1h;
    const __half* Wi0h; const __half* Wi1h;
    const float* bi0; const float* bh0; const float* bi1; const float* bh1;
    float* h0c; float* h1c; float* h1row;
    float* ghb; float* wsrow; float* wscol; float* curc;
    float* out;
};

__global__ __launch_bounds__(1024) void k_loop(LoopArgs P)
{
    cg::grid_group grid = cg::this_grid();
    const int blk = blockIdx.x, t = threadIdx.x;
    const int lane = t & 63, widx = t >> 6;

    __shared__ float h1s[NH], wsp[NH], vs[NH], atts[NH];
    __shared__ float2 attp2[4][256];
    __shared__ float pes[NE], combA[NH], combB[NH], outsh[NT];
    __shared__ float invD_sh;
    __shared__ float red[2][8][64][3];   // gru reduction, 2 j-groups per block

    // ---------------- phase A: att path + ghb precompute --------------------
    auto phaseA = [&](int s, int do_att, const float* h0col, const float* h1col) {
        if (blk < NB) {
            const int b = blk;
            if (t < NH) { h1s[t] = P.h1row[b*NH + t]; vs[t] = P.vattn[t]; }
            else        { wsp[t - NH] = P.wsrow[b*NH + (t - NH)]; }
            __syncthreads();

            if (s > 0) {
                if (widx < NT) {
                    const __half* wr = P.Wouth + (size_t)widx*(2*NH + NF);
                    float o = 0.f;
                    for (int c = lane; c < 2*NH + NF; c += 64) {
                        float x = (c < NH) ? h1s[c]
                                : (c < 2*NH ? wsp[c - NH] : P.curc[(c - 2*NH)*NB + b]);
                        o += __half2float(wr[c]) * x;
                    }
                    #pragma unroll
                    for (int off = 32; off; off >>= 1) o += __shfl_down(o, off);
                    if (lane == 0) {
                        o += P.bout[widx];
                        outsh[widx] = o;
                        P.out[b*(NDEC*NT) + (s-1)*NT + widx] = o;
                    }
                }
                __syncthreads();
                if (do_att) {
                    if (t < NF) P.curc[t*NB + b] = P.inputs[b*(NDEC*NF) + (s-1)*NF + t];
                    __syncthreads();
                    if (t < NT) P.curc[P.tgt[t]*NB + b] = outsh[t];
                }
            }
            if (do_att) {
                // att[g] = h1 . Wa_h[g] + battn[g]
                {
                    int g2 = t & 255, kqa = t >> 8;   // 4 K-quarters of 128
                    float a0 = 0.f, a1 = 0.f;
                    #pragma unroll 4
                    for (int k = kqa*128; k < kqa*128 + 128; ++k) {
                        float2 f = __half22float2(*(const __half2*)(P.WahT + (size_t)k*NH + g2*2));
                        float h = h1s[k];
                        a0 += f.x*h; a1 += f.y*h;
                    }
                    attp2[kqa][g2] = make_float2(a0, a1);
                }
                __syncthreads();
                if (t < NH) {
                    int g = t;
                    float2 p0 = attp2[0][g>>1], p1 = attp2[1][g>>1];
                    float2 p2 = attp2[2][g>>1], p3 = attp2[3][g>>1];
                    float v = (g & 1) ? (p0.y + p1.y + p2.y + p3.y)
                                      : (p0.x + p1.x + p2.x + p3.x);
                    atts[g] = v + P.battn[g];
                }
                __syncthreads();

                // scores -> exp
                {
                    float ar[8], vr[8];
                    #pragma unroll
                    for (int i = 0; i < 8; ++i) { ar[i] = atts[lane*8 + i]; vr[i] = vs[lane*8 + i]; }
                    for (int it = 0; it < 6; ++it) {
                        int e = widx + it*16;
                        const __half* ep = P.encph + ((size_t)(b*NE + e))*NH + lane*8;
                        uint4 u = *(const uint4*)ep;
                        __half2 p0 = *(__half2*)&u.x, p1 = *(__half2*)&u.y;
                        __half2 p2 = *(__half2*)&u.z, p3 = *(__half2*)&u.w;
                        float2 f0 = __half22float2(p0), f1 = __half22float2(p1);
                        float2 f2 = __half22float2(p2), f3 = __half22float2(p3);
                        float sacc;
                        sacc  = fast_tanh(f0.x + ar[0]) * vr[0];
                        sacc += fast_tanh(f0.y + ar[1]) * vr[1];
                        sacc += fast_tanh(f1.x + ar[2]) * vr[2];
                        sacc += fast_tanh(f1.y + ar[3]) * vr[3];
                        sacc += fast_tanh(f2.x + ar[4]) * vr[4];
                        sacc += fast_tanh(f2.y + ar[5]) * vr[5];
                        sacc += fast_tanh(f3.x + ar[6]) * vr[6];
                        sacc += fast_tanh(f3.y + ar[7]) * vr[7];
                        #pragma unroll
                        for (int off = 32; off; off >>= 1) sacc += __shfl_down(sacc, off);
                        if (lane == 0) pes[e] = __expf(sacc);
                    }
                }
                __syncthreads();

                if (t < 64) {
                    float v = pes[t] + ((t < 32) ? pes[64 + t] : 0.f);
                    #pragma unroll
                    for (int off = 32; off; off >>= 1) v += __shfl_down(v, off);
                    if (t == 0) invD_sh = 1.f / v;
                }
                __syncthreads();

                // ws[k] = sum_e p[e] * enc[b,e,k]
                {
                    int k = t & 511, hf = t >> 9;
                    const float* eb = P.enc + ((size_t)b*NE + hf*48)*NH + k;
                    float acc = 0.f;
                    #pragma unroll 4
                    for (int e = 0; e < 48; ++e) acc += pes[hf*48 + e] * eb[(size_t)e*NH];
                    if (hf == 0) combA[k] = acc; else combB[k] = acc;
                }
                __syncthreads();
                if (t < NH) {
                    float v = (combA[t] + combB[t]) * invD_sh;
                    P.wsrow[b*NH + t] = v;
                    P.wscol[t*NB + b] = v;
                }
            }
        } else if (do_att) {
            // ---------- recurrent-half precompute (blocks 64..159) ----------
            int li = blk - NB;                 // 0..95
            int layer = (li >= 48) ? 1 : 0;
            int idx = layer ? (li - 48) : li;  // 0..47
            int b = t & 63, rsub = t >> 6;     // rsub 0..15
            int row0 = idx*32 + rsub*2;        // 2 rows/thread; 32 rows/block
            const __half* Wh = layer ? P.Wh1h : P.Wh0h;
            const float*  st = layer ? h1col : h0col;
            const __half* wrA = Wh + (size_t)(row0    )*NH;
            const __half* wrB = Wh + (size_t)(row0 + 1)*NH;
            float aA = 0.f, aB = 0.f;
            #pragma unroll 8
            for (int k = 0; k < NH; k += 2) {
                float x0 = st[k*NB + b], x1 = st[(k+1)*NB + b];
                float2 fA = __half22float2(*(const __half2*)(wrA + k));
                float2 fB = __half22float2(*(const __half2*)(wrB + k));
                aA += fA.x*x0 + fA.y*x1;
                aB += fB.x*x0 + fB.y*x1;
            }
            float* gdst = P.ghb + (size_t)layer*3*NH*NB;
            gdst[(size_t)(row0    )*NB + b] = aA;
            gdst[(size_t)(row0 + 1)*NB + b] = aB;
        }
    };

    // ---------------- gru phase: input-half + gate combine ------------------
    // 512 j's mapped onto 160 blocks x 2 j-groups x 2 passes.
    auto gruPhase = [&](const __half* Wi, const float* bi, const float* bh,
                        const float* xA, int KA, const float* xB, int KB,
                        const float* ghbL, const float* holdc,
                        float* hnewc, float* hnewrow) {
        const int jsub = t >> 9;            // 0/1 : which j this 512-group does
        const int tt = t & 511;
        const int b = tt & 63, kq = tt >> 6; // kq in [0,8)
        const int KIw = KA + KB;
        for (int p = 0; p < 2; ++p) {
            int jbase = p*320 + blk*2;       // uniform per block
            if (jbase < NH) {                // block-uniform predicate
                int j = jbase + jsub;
                const __half* w0 = Wi + (size_t)j*KIw;
                const __half* w1 = Wi + (size_t)(NH + j)*KIw;
                const __half* w2 = Wi + (size_t)(2*NH + j)*KIw;
                float A0 = 0.f, A1 = 0.f, A2 = 0.f;

                int lenA = KA >> 3;
                #pragma unroll 4
                for (int k = kq*lenA; k < kq*lenA + lenA; k += 2) {
                    float x0 = xA[k*NB + b], x1 = xA[(k+1)*NB + b];
                    float2 f0 = __half22float2(*(const __half2*)(w0 + k));
                    float2 f1 = __half22float2(*(const __half2*)(w1 + k));
                    float2 f2 = __half22float2(*(const __half2*)(w2 + k));
                    A0 += f0.x*x0 + f0.y*x1;
                    A1 += f1.x*x0 + f1.y*x1;
                    A2 += f2.x*x0 + f2.y*x1;
                }
                if (KB > 0) {
                    int lenB = KB >> 3;
                    #pragma unroll 4
                    for (int k = kq*lenB; k < kq*lenB + lenB; k += 2) {
                        float x0 = xB[k*NB + b], x1 = xB[(k+1)*NB + b];
                        int c = KA + k;
                        float2 f0 = __half22float2(*(const __half2*)(w0 + c));
                        float2 f1 = __half22float2(*(const __half2*)(w1 + c));
                        float2 f2 = __half22float2(*(const __half2*)(w2 + c));
                        A0 += f0.x*x0 + f0.y*x1;
                        A1 += f1.x*x0 + f1.y*x1;
                        A2 += f2.x*x0 + f2.y*x1;
                    }
                }

                red[jsub][kq][b][0] = A0; red[jsub][kq][b][1] = A1; red[jsub][kq][b][2] = A2;
                __syncthreads();
                if (tt < 64) {
                    float S0 = 0.f, S1 = 0.f, S2 = 0.f;
                    #pragma unroll
                    for (int q = 0; q < 8; ++q) {
                        S0 += red[jsub][q][tt][0];
                        S1 += red[jsub][q][tt][1];
                        S2 += red[jsub][q][tt][2];
                    }
                    float ghr = ghbL[(size_t)(0*NH + j)*NB + tt];
                    float ghz = ghbL[(size_t)(1*NH + j)*NB + tt];
                    float ghn = ghbL[(size_t)(2*NH + j)*NB + tt];
                    float r = fast_sig(S0 + ghr + bi[j] + bh[j]);
                    float z = fast_sig(S1 + ghz + bi[NH + j] + bh[NH + j]);
                    float n = fast_tanh(S2 + bi[2*NH + j] + r*(ghn + bh[2*NH + j]));
                    float hp = holdc[(size_t)j*NB + tt];
                    float hv = (1.f - z)*n + z*hp;
                    hnewc[(size_t)j*NB + tt] = hv;
                    if (hnewrow) hnewrow[(size_t)tt*NH + j] = hv;
                }
                __syncthreads();   // red reused next pass
            }
        }
    };

    // ---------------------------- main loop ---------------------------------
    for (int s = 0; s < NDEC; ++s) {
        int par = s & 1;
        const float* h0col = P.h0c + par*NH*NB;
        const float* h1col = P.h1c + par*NH*NB;
        float* h0new = P.h0c + (par^1)*NH*NB;
        float* h1new = P.h1c + (par^1)*NH*NB;

        phaseA(s, 1, h0col, h1col);
        grid.sync();
        gruPhase(P.Wi0h, P.bi0, P.bh0, P.curc, NF, P.wscol, NH,
                 P.ghb, h0col, h0new, nullptr);
        grid.sync();
        gruPhase(P.Wi1h, P.bi1, P.bh1, h0new, NH, nullptr, 0,
                 P.ghb + 3*NH*NB, h1col, h1new, P.h1row);
        grid.sync();
    }
    // Final out(11) projection only; h1row holds h1(12)
    phaseA(NDEC, 0, nullptr, nullptr);
}

// ---------------------------------------------------------------------------
extern "C" void kernel_launch(void* const* d_in, const int* in_sizes, int n_in,
                              void* d_out, int out_size, void* d_ws, size_t ws_size,
                              hipStream_t stream) {
    const float* inputs = (const float*)d_in[0];
    const float* hidden = (const float*)d_in[1];
    const float* enc    = (const float*)d_in[2];
    const int*   tgt    = (const int*)d_in[3];
    const float* Wattn  = (const float*)d_in[4];
    const float* battn  = (const float*)d_in[5];
    const float* vattn  = (const float*)d_in[6];
    const float* Wi0    = (const float*)d_in[7];
    const float* Wh0    = (const float*)d_in[8];
    const float* bi0    = (const float*)d_in[9];
    const float* bh0    = (const float*)d_in[10];
    const float* Wi1    = (const float*)d_in[11];
    const float* Wh1    = (const float*)d_in[12];
    const float* bi1    = (const float*)d_in[13];
    const float* bh1    = (const float*)d_in[14];
    const float* Wout   = (const float*)d_in[15];
    const float* bout   = (const float*)d_in[16];
    float* out = (float*)d_out;

    // Workspace (≈14.8 MiB)
    float* h0c   = (float*)d_ws;              // 2 x [512][64]
    float* h1c   = h0c + 2*NH*NB;             // 2 x [512][64]
    float* h1row = h1c + 2*NH*NB;             // [64][512]
    float* wsrow = h1row + NB*NH;             // [64][512]
    float* wscol = wsrow + NB*NH;             // [512][64]
    float* curc  = wscol + NH*NB;             // [32][64]
    float* ghb   = curc + NF*NB;              // [2][3][512][64]
    __half* Wi0h  = (__half*)(ghb + 2*3*NH*NB);  // 1536 x 544
    __half* Wh0h  = Wi0h + 1536*544;          // 1536 x 512
    __half* Wi1h  = Wh0h + 1536*512;
    __half* Wh1h  = Wi1h + 1536*512;
    __half* Wouth = Wh1h + 1536*512;          // 4 x 1056
    __half* WahT  = Wouth + 4*1056;           // [512 k][512 g]
    __half* WaeH  = WahT + 512*512;           // [512 g][512 k] fp16
    __half* encph = WaeH + 512*512;           // [6144][512]

    const int prep_n = 1536*544 + 3*1536*512 + 4*1056 + 2*512*512 + NB*NH + NB*NF;
    k_prep<<<(prep_n + 255)/256, 256, 0, stream>>>(
        Wi0, Wh0, Wi1, Wh1, Wout, Wattn, hidden, inputs,
        Wi0h, Wh0h, Wi1h, Wh1h, Wouth, WahT, WaeH, h0c, h1c, h1row, curc);
    k_encproj<<<768, 256, 0, stream>>>(enc, WaeH, encph);

    LoopArgs la;
    la.inputs = inputs; la.tgt = tgt;
    la.WahT = WahT; la.battn = battn; la.vattn = vattn;
    la.Wouth = Wouth; la.bout = bout;
    la.encph = encph; la.enc = enc;
    la.Wh0h = Wh0h; la.Wh1h = Wh1h;
    la.Wi0h = Wi0h; la.Wi1h = Wi1h;
    la.bi0 = bi0; la.bh0 = bh0; la.bi1 = bi1; la.bh1 = bh1;
    la.h0c = h0c; la.h1c = h1c; la.h1row = h1row;
    la.ghb = ghb; la.wsrow = wsrow; la.wscol = wscol; la.curc = curc;
    la.out = out;
    void* kargs[] = { (void*)&la };
    hipLaunchCooperativeKernel((const void*)k_loop, dim3(NB + 96), dim3(1024),
                               kargs, 0, stream);
}

// Round 2
// 1298.005 us; speedup vs baseline: 1.4445x; 1.4445x over previous
//
#include <hip/hip_runtime.h>
#include <hip/hip_fp16.h>

// Problem constants
#define NB   64     // batch
#define NDEC 12     // decoder steps
#define NF   32     // input features
#define NH   512    // hidden
#define NE   96     // encoder length
#define NT   4      // output dim
#define KI0  (NF + NH)   // 544 = K of layer-0 input GEMM

typedef _Float16 half8_t __attribute__((ext_vector_type(8)));
typedef float   float4_t __attribute__((ext_vector_type(4)));

__device__ __forceinline__ float fast_tanh(float x) {
    x = fminf(fmaxf(x, -15.f), 15.f);
    float e = __expf(2.f * x);
    return (e - 1.f) / (e + 1.f);
}
__device__ __forceinline__ float fast_sig(float x) {
    return 1.f / (1.f + __expf(-x));
}

// ---------------------------------------------------------------------------
// One-time: fp32->fp16 weight converts (+ Wa_h transpose, Wa_e fp16) + state init.
__global__ __launch_bounds__(256) void k_prep(
    const float* __restrict__ Wi0, const float* __restrict__ Wh0,
    const float* __restrict__ Wi1, const float* __restrict__ Wh1,
    const float* __restrict__ Wout, const float* __restrict__ Wattn,
    const float* __restrict__ hidden, const float* __restrict__ inputs,
    __half* __restrict__ Wi0h, __half* __restrict__ Wh0h,
    __half* __restrict__ Wi1h, __half* __restrict__ Wh1h,
    __half* __restrict__ Wouth, __half* __restrict__ WahT,
    __half* __restrict__ WaeH,
    float* __restrict__ h0row, float* __restrict__ h1row,
    __half* __restrict__ h0h, __half* __restrict__ h1h,
    float* __restrict__ currow, __half* __restrict__ xcat_h)
{
    int i = blockIdx.x*256 + threadIdx.x;
    const int n0 = 1536*KI0, n1 = 1536*512, n4 = 4*1056, n5 = 512*512;
    if (i < n0) { Wi0h[i] = __float2half_rn(Wi0[i]); return; }  i -= n0;
    if (i < n1) { Wh0h[i] = __float2half_rn(Wh0[i]); return; }  i -= n1;
    if (i < n1) { Wi1h[i] = __float2half_rn(Wi1[i]); return; }  i -= n1;
    if (i < n1) { Wh1h[i] = __float2half_rn(Wh1[i]); return; }  i -= n1;
    if (i < n4) { Wouth[i] = __float2half_rn(Wout[i]); return; } i -= n4;
    if (i < n5) {
        int k = i >> 9, g = i & 511;                 // WahT[k][g] = Wattn[g][k]
        WahT[i] = __float2half_rn(Wattn[(size_t)g*1024 + k]);
        return;
    }
    i -= n5;
    if (i < n5) {                                     // WaeH[g][k] = Wattn[g][512+k]
        int g = i >> 9, k = i & 511;
        WaeH[i] = __float2half_rn(Wattn[(size_t)g*1024 + 512 + k]);
        return;
    }
    i -= n5;
    if (i < NB*NH) {                                  // state init (row-major)
        int b = i >> 9, k = i & 511;
        float v0 = hidden[b*NH + k];
        float v1 = hidden[NB*NH + b*NH + k];
        h0row[b*NH + k] = v0;  h0h[b*NH + k] = __float2half_rn(v0);
        h1row[b*NH + k] = v1;  h1h[b*NH + k] = __float2half_rn(v1);
        return;
    }
    i -= NB*NH;
    if (i < NB*NF) {                                  // cur(0)
        int b = i >> 5, k = i & 31;
        float v = inputs[b*NDEC*NF + k];
        currow[b*NF + k] = v;
        xcat_h[(size_t)b*KI0 + k] = __float2half_rn(v);
    }
}

// ---------------------------------------------------------------------------
// enc_proj via MFMA f16: encp[be][g] = sum_k enc[be][k] * WaeH[g][k].
// Verified fragment layout: A[m=lane&15][k=(lane>>4)*8+i], B[n=lane&15][k...],
// D[row=(lane>>4)*4+r][col=lane&15].
__global__ __launch_bounds__(256) void k_encproj(const float* __restrict__ enc,
                                                 const __half* __restrict__ WaeH,
                                                 __half* __restrict__ encph) {
    int x = blockIdx.x;                 // 768 = 96 (m-tiles) x 8 (n-tiles)
    int by = x >> 3, bx = x & 7;
    int t = threadIdx.x, w = t >> 6, lane = t & 63;
    int mr = lane & 15, kq = lane >> 4;          // kq in 0..3
    int m = by*64 + w*16 + mr;
    const float* arow = enc + (size_t)m*NH;
    float4_t acc[4] = {{0.f,0.f,0.f,0.f},{0.f,0.f,0.f,0.f},
                       {0.f,0.f,0.f,0.f},{0.f,0.f,0.f,0.f}};
    for (int kb = 0; kb < NH; kb += 32) {
        int k = kb + kq*8;
        float4 a0 = *(const float4*)(arow + k);
        float4 a1 = *(const float4*)(arow + k + 4);
        half8_t a;
        a[0] = (_Float16)a0.x; a[1] = (_Float16)a0.y;
        a[2] = (_Float16)a0.z; a[3] = (_Float16)a0.w;
        a[4] = (_Float16)a1.x; a[5] = (_Float16)a1.y;
        a[6] = (_Float16)a1.z; a[7] = (_Float16)a1.w;
        #pragma unroll
        for (int j = 0; j < 4; ++j) {
            int n = bx*64 + j*16 + mr;
            half8_t b = *(const half8_t*)(WaeH + (size_t)n*NH + k);
            acc[j] = __builtin_amdgcn_mfma_f32_16x16x32_f16(a, b, acc[j], 0, 0, 0);
        }
    }
    #pragma unroll
    for (int j = 0; j < 4; ++j) {
        int col = bx*64 + j*16 + mr;
        #pragma unroll
        for (int r = 0; r < 4; ++r) {
            int row = by*64 + w*16 + kq*4 + r;
            encph[(size_t)row*NH + col] = __float2half_rn(acc[j][r]);
        }
    }
}

// ---------------------------------------------------------------------------
// Per-step kernel D1. grid = 64 (+12 when do_att):
//  blocks 0..63 : out-proj(s-1) + cur(s) + att GEMV + scores + softmax + ws
//  blocks 64..75: ghb[layer][row][b] = Wh @ h  via MFMA (M=1536,K=512,N=64 x2)
__global__ __launch_bounds__(1024) void k_step(
    const float* __restrict__ inputs, const int* __restrict__ tgt,
    const __half* __restrict__ WahT,   // [512 k][512 g]
    const float* __restrict__ battn, const float* __restrict__ vattn,
    const __half* __restrict__ Wouth, const float* __restrict__ bout,
    const __half* __restrict__ encph, const float* __restrict__ enc,
    const __half* __restrict__ Wh0h, const __half* __restrict__ Wh1h,
    const __half* __restrict__ h0h,    // [64][512] fp16 h0(s)
    const __half* __restrict__ h1h,    // [64][512] fp16 h1(s)
    const float* __restrict__ h1row,   // [64][512] fp32 h1(s)
    float* __restrict__ wsrow,         // [64][512]
    float* __restrict__ currow,        // [64][32]
    __half* __restrict__ xcat_h,       // [64][544] = [cur | ws] fp16
    float* __restrict__ ghb,           // [2][3*512][64]
    float* __restrict__ out,
    int s, int do_att)
{
    int blk = blockIdx.x, t = threadIdx.x;
    int lane = t & 63, widx = t >> 6;

    if (blk >= NB) {
        // ---------------- ghb via MFMA ----------------
        int li = blk - NB;                 // 0..11
        int layer = (li >= 6) ? 1 : 0;
        int mblk = layer ? (li - 6) : li;  // 0..5
        int mr = lane & 15, kq = lane >> 4;
        int row0 = mblk*256 + widx*16;     // wave's 16 rows within layer
        const __half* Wh = layer ? Wh1h : Wh0h;
        const __half* Xh = layer ? h1h : h0h;
        const __half* arow = Wh + (size_t)(row0 + mr)*NH;
        float4_t acc[4] = {{0.f,0.f,0.f,0.f},{0.f,0.f,0.f,0.f},
                           {0.f,0.f,0.f,0.f},{0.f,0.f,0.f,0.f}};
        for (int kb = 0; kb < NH; kb += 32) {
            half8_t a = *(const half8_t*)(arow + kb + kq*8);
            #pragma unroll
            for (int nt = 0; nt < 4; ++nt) {
                half8_t bb = *(const half8_t*)(Xh + (size_t)(nt*16 + mr)*NH + kb + kq*8);
                acc[nt] = __builtin_amdgcn_mfma_f32_16x16x32_f16(a, bb, acc[nt], 0, 0, 0);
            }
        }
        float* gdst = ghb + (size_t)(layer*3*NH + row0)*NB;
        #pragma unroll
        for (int nt = 0; nt < 4; ++nt) {
            #pragma unroll
            for (int r = 0; r < 4; ++r) {
                gdst[(size_t)(kq*4 + r)*NB + nt*16 + mr] = acc[nt][r];
            }
        }
        return;
    }

    int b = blk;
    __shared__ float h1s[NH], wsp[NH], vs[NH], atts[NH];
    __shared__ float2 attp2[4][256];
    __shared__ float pes[NE], combA[NH], combB[NH], outsh[NT];
    __shared__ float invD_sh;

    if (t < NH) { h1s[t] = h1row[b*NH + t]; vs[t] = vattn[t]; }
    else        { wsp[t - NH] = wsrow[b*NH + (t - NH)]; }
    __syncthreads();

    if (s > 0) {
        if (widx < NT) {
            const __half* wr = Wouth + (size_t)widx*(2*NH + NF);
            float o = 0.f;
            for (int c = lane; c < 2*NH + NF; c += 64) {
                float x = (c < NH) ? h1s[c]
                        : (c < 2*NH ? wsp[c - NH] : currow[b*NF + (c - 2*NH)]);
                o += __half2float(wr[c]) * x;
            }
            #pragma unroll
            for (int off = 32; off; off >>= 1) o += __shfl_down(o, off);
            if (lane == 0) {
                o += bout[widx];
                outsh[widx] = o;
                out[b*(NDEC*NT) + (s-1)*NT + widx] = o;
            }
        }
        __syncthreads();
        if (do_att) {
            if (t < NF) {
                float v = inputs[b*(NDEC*NF) + (s-1)*NF + t];
                currow[b*NF + t] = v;
                xcat_h[(size_t)b*KI0 + t] = __float2half_rn(v);
            }
            __syncthreads();
            if (t < NT) {
                int ti = tgt[t];
                float v = outsh[t];
                currow[b*NF + ti] = v;
                xcat_h[(size_t)b*KI0 + ti] = __float2half_rn(v);
            }
        }
    }
    if (!do_att) return;

    // att[g] = h1 . Wa_h[g] + battn[g]; coalesced: lane covers g-pairs
    {
        int g2 = t & 255, kqa = t >> 8;   // 4 K-quarters of 128
        float a0 = 0.f, a1 = 0.f;
        #pragma unroll 4
        for (int k = kqa*128; k < kqa*128 + 128; ++k) {
            float2 f = __half22float2(*(const __half2*)(WahT + (size_t)k*NH + g2*2));
            float h = h1s[k];
            a0 += f.x*h; a1 += f.y*h;
        }
        attp2[kqa][g2] = make_float2(a0, a1);
    }
    __syncthreads();
    if (t < NH) {
        int g = t;
        float2 p0 = attp2[0][g>>1], p1 = attp2[1][g>>1];
        float2 p2 = attp2[2][g>>1], p3 = attp2[3][g>>1];
        float v = (g & 1) ? (p0.y + p1.y + p2.y + p3.y)
                          : (p0.x + p1.x + p2.x + p3.x);
        atts[g] = v + battn[g];
    }
    __syncthreads();

    // scores -> exp (no max-subtract: |score| small)
    {
        float ar[8], vr[8];
        #pragma unroll
        for (int i = 0; i < 8; ++i) { ar[i] = atts[lane*8 + i]; vr[i] = vs[lane*8 + i]; }
        for (int it = 0; it < 6; ++it) {
            int e = widx + it*16;
            const __half* ep = encph + ((size_t)(b*NE + e))*NH + lane*8;
            uint4 u = *(const uint4*)ep;
            __half2 p0 = *(__half2*)&u.x, p1 = *(__half2*)&u.y;
            __half2 p2 = *(__half2*)&u.z, p3 = *(__half2*)&u.w;
            float2 f0 = __half22float2(p0), f1 = __half22float2(p1);
            float2 f2 = __half22float2(p2), f3 = __half22float2(p3);
            float sacc;
            sacc  = fast_tanh(f0.x + ar[0]) * vr[0];
            sacc += fast_tanh(f0.y + ar[1]) * vr[1];
            sacc += fast_tanh(f1.x + ar[2]) * vr[2];
            sacc += fast_tanh(f1.y + ar[3]) * vr[3];
            sacc += fast_tanh(f2.x + ar[4]) * vr[4];
            sacc += fast_tanh(f2.y + ar[5]) * vr[5];
            sacc += fast_tanh(f3.x + ar[6]) * vr[6];
            sacc += fast_tanh(f3.y + ar[7]) * vr[7];
            #pragma unroll
            for (int off = 32; off; off >>= 1) sacc += __shfl_down(sacc, off);
            if (lane == 0) pes[e] = __expf(sacc);
        }
    }
    __syncthreads();

    if (t < 64) {
        float v = pes[t] + ((t < 32) ? pes[64 + t] : 0.f);
        #pragma unroll
        for (int off = 32; off; off >>= 1) v += __shfl_down(v, off);
        if (t == 0) invD_sh = 1.f / v;
    }
    __syncthreads();

    // ws[k] = sum_e p[e] * enc[b,e,k]  (coalesced over k)
    {
        int k = t & 511, half = t >> 9;
        const float* eb = enc + ((size_t)b*NE + half*48)*NH + k;
        float acc = 0.f;
        #pragma unroll 4
        for (int e = 0; e < 48; ++e) acc += pes[half*48 + e] * eb[(size_t)e*NH];
        if (half == 0) combA[k] = acc; else combB[k] = acc;
    }
    __syncthreads();
    if (t < NH) {
        float v = (combA[t] + combB[t]) * invD_sh;
        wsrow[b*NH + t] = v;
        xcat_h[(size_t)b*KI0 + NF + t] = __float2half_rn(v);
    }
}

// ---------------------------------------------------------------------------
// GRU input-half via MFMA + gate combine. grid 8 blocks x 1024.
// Block owns 64 j's: rows {j.., 512+j.., 1024+j..} (3 gates x 64 = 12 m-tiles).
// Waves 0..11: MFMA (gate = w>>2, msub = w&3) -> gis LDS; then combine.
__global__ __launch_bounds__(1024) void k_gru(
    const __half* __restrict__ Wi,
    const float* __restrict__ bi, const float* __restrict__ bh,
    const __half* __restrict__ xh, int K,     // [64][K] fp16
    const float* __restrict__ ghbL,           // [3*512][64] Wh . hold
    const float* __restrict__ hold,           // [64][512] fp32
    float* __restrict__ hnew,                 // [64][512] fp32 (may == hold)
    __half* __restrict__ hnewh)               // [64][512] fp16
{
    int blk = blockIdx.x, t = threadIdx.x;
    int w = t >> 6, lane = t & 63;
    int mr = lane & 15, kq = lane >> 4;
    int jbase = blk*64;
    __shared__ float gis[3][64][65];          // +1 pad: conflict-free j-major reads

    if (w < 12) {
        int gate = w >> 2, msub = w & 3;
        int row0 = gate*NH + jbase + msub*16;
        const __half* arow = Wi + (size_t)(row0 + mr)*K;
        float4_t acc[4] = {{0.f,0.f,0.f,0.f},{0.f,0.f,0.f,0.f},
                           {0.f,0.f,0.f,0.f},{0.f,0.f,0.f,0.f}};
        for (int kb = 0; kb < K; kb += 32) {
            half8_t a = *(const half8_t*)(arow + kb + kq*8);
            #pragma unroll
            for (int nt = 0; nt < 4; ++nt) {
                half8_t bb = *(const half8_t*)(xh + (size_t)(nt*16 + mr)*K + kb + kq*8);
                acc[nt] = __builtin_amdgcn_mfma_f32_16x16x32_f16(a, bb, acc[nt], 0, 0, 0);
            }
        }
        #pragma unroll
        for (int nt = 0; nt < 4; ++nt) {
            #pragma unroll
            for (int r = 0; r < 4; ++r) {
                gis[gate][msub*16 + kq*4 + r][nt*16 + mr] = acc[nt][r];
            }
        }
    }
    __syncthreads();

    // combine: thread (jl = t&63) handles 4 batches
    int jl = t & 63;
    int j = jbase + jl;
    float biR = bi[j],        bhR = bh[j];
    float biZ = bi[NH + j],   bhZ = bh[NH + j];
    float biN = bi[2*NH + j], bhN = bh[2*NH + j];
    #pragma unroll
    for (int q = 0; q < 4; ++q) {
        int b = (t >> 6) + q*16;
        float S0 = gis[0][jl][b], S1 = gis[1][jl][b], S2 = gis[2][jl][b];
        float ghr = ghbL[(size_t)(0*NH + j)*NB + b];
        float ghz = ghbL[(size_t)(1*NH + j)*NB + b];
        float ghn = ghbL[(size_t)(2*NH + j)*NB + b];
        float r = fast_sig(S0 + ghr + biR + bhR);
        float z = fast_sig(S1 + ghz + biZ + bhZ);
        float n = fast_tanh(S2 + biN + r*(ghn + bhN));
        float hp = hold[(size_t)b*NH + j];
        float hv = (1.f - z)*n + z*hp;
        hnew[(size_t)b*NH + j] = hv;
        hnewh[(size_t)b*NH + j] = __float2half_rn(hv);
    }
}

// ---------------------------------------------------------------------------
extern "C" void kernel_launch(void* const* d_in, const int* in_sizes, int n_in,
                              void* d_out, int out_size, void* d_ws, size_t ws_size,
                              hipStream_t stream) {
    const float* inputs = (const float*)d_in[0];
    const float* hidden = (const float*)d_in[1];
    const float* enc    = (const float*)d_in[2];
    const int*   tgt    = (const int*)d_in[3];
    const float* Wattn  = (const float*)d_in[4];
    const float* battn  = (const float*)d_in[5];
    const float* vattn  = (const float*)d_in[6];
    const float* Wi0    = (const float*)d_in[7];
    const float* Wh0    = (const float*)d_in[8];
    const float* bi0    = (const float*)d_in[9];
    const float* bh0    = (const float*)d_in[10];
    const float* Wi1    = (const float*)d_in[11];
    const float* Wh1    = (const float*)d_in[12];
    const float* bi1    = (const float*)d_in[13];
    const float* bh1    = (const float*)d_in[14];
    const float* Wout   = (const float*)d_in[15];
    const float* bout   = (const float*)d_in[16];
    float* out = (float*)d_out;

    // Workspace (~15.1 MiB)
    float* h0row  = (float*)d_ws;             // [64][512]
    float* h1row  = h0row + NB*NH;            // [64][512]
    float* wsrow  = h1row + NB*NH;            // [64][512]
    float* currow = wsrow + NB*NH;            // [64][32]
    float* ghb    = currow + NB*NF;           // [2][3*512][64]
    __half* Wi0h  = (__half*)(ghb + 2*3*NH*NB);  // 1536 x 544
    __half* Wh0h  = Wi0h + 1536*KI0;          // 1536 x 512
    __half* Wi1h  = Wh0h + 1536*NH;           // 1536 x 512
    __half* Wh1h  = Wi1h + 1536*NH;           // 1536 x 512
    __half* Wouth = Wh1h + 1536*NH;           // 4 x 1056
    __half* WahT  = Wouth + 4*1056;           // [512 k][512 g]
    __half* WaeH  = WahT + NH*NH;             // [512 g][512 k]
    __half* h0h   = WaeH + NH*NH;             // [64][512]
    __half* h1h   = h0h + NB*NH;              // [64][512]
    __half* xcat_h= h1h + NB*NH;              // [64][544]
    __half* encph = xcat_h + NB*KI0;          // [6144][512]

    const int prep_n = 1536*KI0 + 3*1536*NH + 4*1056 + 2*NH*NH + NB*NH + NB*NF;
    k_prep<<<(prep_n + 255)/256, 256, 0, stream>>>(
        Wi0, Wh0, Wi1, Wh1, Wout, Wattn, hidden, inputs,
        Wi0h, Wh0h, Wi1h, Wh1h, Wouth, WahT, WaeH,
        h0row, h1row, h0h, h1h, currow, xcat_h);
    k_encproj<<<768, 256, 0, stream>>>(enc, WaeH, encph);

    for (int s = 0; s < NDEC; ++s) {
        k_step<<<NB + 12, 1024, 0, stream>>>(
            inputs, tgt, WahT, battn, vattn, Wouth, bout, encph, enc,
            Wh0h, Wh1h, h0h, h1h, h1row,
            wsrow, currow, xcat_h, ghb, out, s, 1);
        k_gru<<<8, 1024, 0, stream>>>(Wi0h, bi0, bh0,
                                      xcat_h, KI0,
                                      ghb,
                                      h0row, h0row, h0h);
        k_gru<<<8, 1024, 0, stream>>>(Wi1h, bi1, bh1,
                                      h0h, NH,
                                      ghb + 3*NH*NB,
                                      h1row, h1row, h1h);
    }
    // Final out(11) projection only; h1row holds h1(12)
    k_step<<<NB, 1024, 0, stream>>>(
        inputs, tgt, WahT, battn, vattn, Wouth, bout, encph, enc,
        Wh0h, Wh1h, h0h, h1h, h1row,
        wsrow, currow, xcat_h, ghb, out, NDEC, 0);
}

// Round 3
// 694.019 us; speedup vs baseline: 2.7017x; 1.8703x over previous
//
#include <hip/hip_runtime.h>
#include <hip/hip_fp16.h>

// Problem constants
#define NB   64     // batch
#define NDEC 12     // decoder steps
#define NF   32     // input features
#define NH   512    // hidden
#define NE   96     // encoder length
#define NT   4      // output dim
#define KI0  (NF + NH)   // 544 = K of layer-0 input GEMM

typedef _Float16 half8_t __attribute__((ext_vector_type(8)));
typedef float   float4_t __attribute__((ext_vector_type(4)));

__device__ __forceinline__ float fast_tanh(float x) {
    x = fminf(fmaxf(x, -15.f), 15.f);
    float e = __expf(2.f * x);
    return (e - 1.f) / (e + 1.f);
}
__device__ __forceinline__ float fast_sig(float x) {
    return 1.f / (1.f + __expf(-x));
}

// ---------------------------------------------------------------------------
// One-time: fp32->fp16 weight converts (+ Wa_h transpose, Wa_e fp16) + state init.
__global__ __launch_bounds__(256) void k_prep(
    const float* __restrict__ Wi0, const float* __restrict__ Wh0,
    const float* __restrict__ Wi1, const float* __restrict__ Wh1,
    const float* __restrict__ Wout, const float* __restrict__ Wattn,
    const float* __restrict__ hidden, const float* __restrict__ inputs,
    __half* __restrict__ Wi0h, __half* __restrict__ Wh0h,
    __half* __restrict__ Wi1h, __half* __restrict__ Wh1h,
    __half* __restrict__ Wouth, __half* __restrict__ WahT,
    __half* __restrict__ WaeH,
    float* __restrict__ h0row, float* __restrict__ h1row,
    __half* __restrict__ h0h, __half* __restrict__ h1h,
    float* __restrict__ currow, __half* __restrict__ xcat_h)
{
    int i = blockIdx.x*256 + threadIdx.x;
    const int n0 = 1536*KI0, n1 = 1536*512, n4 = 4*1056, n5 = 512*512;
    if (i < n0) { Wi0h[i] = __float2half_rn(Wi0[i]); return; }  i -= n0;
    if (i < n1) { Wh0h[i] = __float2half_rn(Wh0[i]); return; }  i -= n1;
    if (i < n1) { Wi1h[i] = __float2half_rn(Wi1[i]); return; }  i -= n1;
    if (i < n1) { Wh1h[i] = __float2half_rn(Wh1[i]); return; }  i -= n1;
    if (i < n4) { Wouth[i] = __float2half_rn(Wout[i]); return; } i -= n4;
    if (i < n5) {
        int k = i >> 9, g = i & 511;                 // WahT[k][g] = Wattn[g][k]
        WahT[i] = __float2half_rn(Wattn[(size_t)g*1024 + k]);
        return;
    }
    i -= n5;
    if (i < n5) {                                     // WaeH[g][k] = Wattn[g][512+k]
        int g = i >> 9, k = i & 511;
        WaeH[i] = __float2half_rn(Wattn[(size_t)g*1024 + 512 + k]);
        return;
    }
    i -= n5;
    if (i < NB*NH) {                                  // state init (row-major)
        int b = i >> 9, k = i & 511;
        float v0 = hidden[b*NH + k];
        float v1 = hidden[NB*NH + b*NH + k];
        h0row[b*NH + k] = v0;  h0h[b*NH + k] = __float2half_rn(v0);
        h1row[b*NH + k] = v1;  h1h[b*NH + k] = __float2half_rn(v1);
        return;
    }
    i -= NB*NH;
    if (i < NB*NF) {                                  // cur(0)
        int b = i >> 5, k = i & 31;
        float v = inputs[b*NDEC*NF + k];
        currow[b*NF + k] = v;
        xcat_h[(size_t)b*KI0 + k] = __float2half_rn(v);
    }
}

// ---------------------------------------------------------------------------
// enc_proj via MFMA f16: encp[be][g] = sum_k enc[be][k] * WaeH[g][k].
// Verified fragment layout: A[m=lane&15][k=(lane>>4)*8+i], B[n=lane&15][k...],
// D[row=(lane>>4)*4+r][col=lane&15].
__global__ __launch_bounds__(256) void k_encproj(const float* __restrict__ enc,
                                                 const __half* __restrict__ WaeH,
                                                 __half* __restrict__ encph) {
    int x = blockIdx.x;                 // 768 = 96 (m-tiles) x 8 (n-tiles)
    int by = x >> 3, bx = x & 7;
    int t = threadIdx.x, w = t >> 6, lane = t & 63;
    int mr = lane & 15, kq = lane >> 4;          // kq in 0..3
    int m = by*64 + w*16 + mr;
    const float* arow = enc + (size_t)m*NH;
    float4_t acc[4] = {{0.f,0.f,0.f,0.f},{0.f,0.f,0.f,0.f},
                       {0.f,0.f,0.f,0.f},{0.f,0.f,0.f,0.f}};
    for (int kb = 0; kb < NH; kb += 32) {
        int k = kb + kq*8;
        float4 a0 = *(const float4*)(arow + k);
        float4 a1 = *(const float4*)(arow + k + 4);
        half8_t a;
        a[0] = (_Float16)a0.x; a[1] = (_Float16)a0.y;
        a[2] = (_Float16)a0.z; a[3] = (_Float16)a0.w;
        a[4] = (_Float16)a1.x; a[5] = (_Float16)a1.y;
        a[6] = (_Float16)a1.z; a[7] = (_Float16)a1.w;
        #pragma unroll
        for (int j = 0; j < 4; ++j) {
            int n = bx*64 + j*16 + mr;
            half8_t b = *(const half8_t*)(WaeH + (size_t)n*NH + k);
            acc[j] = __builtin_amdgcn_mfma_f32_16x16x32_f16(a, b, acc[j], 0, 0, 0);
        }
    }
    #pragma unroll
    for (int j = 0; j < 4; ++j) {
        int col = bx*64 + j*16 + mr;
        #pragma unroll
        for (int r = 0; r < 4; ++r) {
            int row = by*64 + w*16 + kq*4 + r;
            encph[(size_t)row*NH + col] = __float2half_rn(acc[j][r]);
        }
    }
}

// ---------------------------------------------------------------------------
// Per-step kernel D1. grid = 64 (+48 when do_att):
//  blocks 0..63 : out-proj(s-1) + cur(s) + att GEMV + scores + softmax + ws
//  blocks 64..111: ghb[layer][row][b] = Wh @ h via MFMA.
//    16 waves/block, wave = one 16x16 tile: rowtile rt = li*4 + (w>>2) in
//    [0,192) (layer = rt>=96), batch-quarter bq = w&3. A-rows shared across
//    the 4 bq waves of a rowtile via L1 (same CU).
__global__ __launch_bounds__(1024) void k_step(
    const float* __restrict__ inputs, const int* __restrict__ tgt,
    const __half* __restrict__ WahT,   // [512 k][512 g]
    const float* __restrict__ battn, const float* __restrict__ vattn,
    const __half* __restrict__ Wouth, const float* __restrict__ bout,
    const __half* __restrict__ encph, const float* __restrict__ enc,
    const __half* __restrict__ Wh0h, const __half* __restrict__ Wh1h,
    const __half* __restrict__ h0h,    // [64][512] fp16 h0(s)
    const __half* __restrict__ h1h,    // [64][512] fp16 h1(s)
    const float* __restrict__ h1row,   // [64][512] fp32 h1(s)
    float* __restrict__ wsrow,         // [64][512]
    float* __restrict__ currow,        // [64][32]
    __half* __restrict__ xcat_h,       // [64][544] = [cur | ws] fp16
    float* __restrict__ ghb,           // [2][3*512][64]
    float* __restrict__ out,
    int s, int do_att)
{
    int blk = blockIdx.x, t = threadIdx.x;
    int lane = t & 63, widx = t >> 6;

    if (blk >= NB) {
        // ---------------- ghb via MFMA (16x16 tiles) ----------------
        int li = blk - NB;                  // 0..47
        int mr = lane & 15, kq = lane >> 4;
        int rt = li*4 + (widx >> 2);        // global rowtile 0..191
        int bq = widx & 3;
        int layer = (rt >= 96) ? 1 : 0;
        int rloc = (rt - layer*96) * 16;    // row within layer's 1536
        const __half* Wh = layer ? Wh1h : Wh0h;
        const __half* Xh = layer ? h1h : h0h;
        const __half* arow = Wh + (size_t)(rloc + mr)*NH;
        const __half* brow = Xh + (size_t)(bq*16 + mr)*NH;
        float4_t acc = {0.f,0.f,0.f,0.f};
        #pragma unroll 4
        for (int kb = 0; kb < NH; kb += 32) {
            half8_t a = *(const half8_t*)(arow + kb + kq*8);
            half8_t b = *(const half8_t*)(brow + kb + kq*8);
            acc = __builtin_amdgcn_mfma_f32_16x16x32_f16(a, b, acc, 0, 0, 0);
        }
        float* gdst = ghb + ((size_t)layer*3*NH + rloc)*NB;
        #pragma unroll
        for (int r = 0; r < 4; ++r) {
            gdst[(size_t)(kq*4 + r)*NB + bq*16 + mr] = acc[r];
        }
        return;
    }

    int b = blk;
    __shared__ float h1s[NH], wsp[NH], vs[NH], atts[NH];
    __shared__ float2 attp2[4][256];
    __shared__ float pes[NE], combA[NH], combB[NH], outsh[NT];
    __shared__ float invD_sh;

    if (t < NH) { h1s[t] = h1row[b*NH + t]; vs[t] = vattn[t]; }
    else        { wsp[t - NH] = wsrow[b*NH + (t - NH)]; }
    __syncthreads();

    if (s > 0) {
        if (widx < NT) {
            const __half* wr = Wouth + (size_t)widx*(2*NH + NF);
            float o = 0.f;
            for (int c = lane; c < 2*NH + NF; c += 64) {
                float x = (c < NH) ? h1s[c]
                        : (c < 2*NH ? wsp[c - NH] : currow[b*NF + (c - 2*NH)]);
                o += __half2float(wr[c]) * x;
            }
            #pragma unroll
            for (int off = 32; off; off >>= 1) o += __shfl_down(o, off);
            if (lane == 0) {
                o += bout[widx];
                outsh[widx] = o;
                out[b*(NDEC*NT) + (s-1)*NT + widx] = o;
            }
        }
        __syncthreads();
        if (do_att) {
            if (t < NF) {
                float v = inputs[b*(NDEC*NF) + (s-1)*NF + t];
                currow[b*NF + t] = v;
                xcat_h[(size_t)b*KI0 + t] = __float2half_rn(v);
            }
            __syncthreads();
            if (t < NT) {
                int ti = tgt[t];
                float v = outsh[t];
                currow[b*NF + ti] = v;
                xcat_h[(size_t)b*KI0 + ti] = __float2half_rn(v);
            }
        }
    }
    if (!do_att) return;

    // att[g] = h1 . Wa_h[g] + battn[g]; coalesced: lane covers g-pairs
    {
        int g2 = t & 255, kqa = t >> 8;   // 4 K-quarters of 128
        float a0 = 0.f, a1 = 0.f;
        #pragma unroll 4
        for (int k = kqa*128; k < kqa*128 + 128; ++k) {
            float2 f = __half22float2(*(const __half2*)(WahT + (size_t)k*NH + g2*2));
            float h = h1s[k];
            a0 += f.x*h; a1 += f.y*h;
        }
        attp2[kqa][g2] = make_float2(a0, a1);
    }
    __syncthreads();
    if (t < NH) {
        int g = t;
        float2 p0 = attp2[0][g>>1], p1 = attp2[1][g>>1];
        float2 p2 = attp2[2][g>>1], p3 = attp2[3][g>>1];
        float v = (g & 1) ? (p0.y + p1.y + p2.y + p3.y)
                          : (p0.x + p1.x + p2.x + p3.x);
        atts[g] = v + battn[g];
    }
    __syncthreads();

    // scores -> exp (no max-subtract: |score| small)
    {
        float ar[8], vr[8];
        #pragma unroll
        for (int i = 0; i < 8; ++i) { ar[i] = atts[lane*8 + i]; vr[i] = vs[lane*8 + i]; }
        for (int it = 0; it < 6; ++it) {
            int e = widx + it*16;
            const __half* ep = encph + ((size_t)(b*NE + e))*NH + lane*8;
            uint4 u = *(const uint4*)ep;
            __half2 p0 = *(__half2*)&u.x, p1 = *(__half2*)&u.y;
            __half2 p2 = *(__half2*)&u.z, p3 = *(__half2*)&u.w;
            float2 f0 = __half22float2(p0), f1 = __half22float2(p1);
            float2 f2 = __half22float2(p2), f3 = __half22float2(p3);
            float sacc;
            sacc  = fast_tanh(f0.x + ar[0]) * vr[0];
            sacc += fast_tanh(f0.y + ar[1]) * vr[1];
            sacc += fast_tanh(f1.x + ar[2]) * vr[2];
            sacc += fast_tanh(f1.y + ar[3]) * vr[3];
            sacc += fast_tanh(f2.x + ar[4]) * vr[4];
            sacc += fast_tanh(f2.y + ar[5]) * vr[5];
            sacc += fast_tanh(f3.x + ar[6]) * vr[6];
            sacc += fast_tanh(f3.y + ar[7]) * vr[7];
            #pragma unroll
            for (int off = 32; off; off >>= 1) sacc += __shfl_down(sacc, off);
            if (lane == 0) pes[e] = __expf(sacc);
        }
    }
    __syncthreads();

    if (t < 64) {
        float v = pes[t] + ((t < 32) ? pes[64 + t] : 0.f);
        #pragma unroll
        for (int off = 32; off; off >>= 1) v += __shfl_down(v, off);
        if (t == 0) invD_sh = 1.f / v;
    }
    __syncthreads();

    // ws[k] = sum_e p[e] * enc[b,e,k]  (coalesced over k)
    {
        int k = t & 511, half = t >> 9;
        const float* eb = enc + ((size_t)b*NE + half*48)*NH + k;
        float acc = 0.f;
        #pragma unroll 4
        for (int e = 0; e < 48; ++e) acc += pes[half*48 + e] * eb[(size_t)e*NH];
        if (half == 0) combA[k] = acc; else combB[k] = acc;
    }
    __syncthreads();
    if (t < NH) {
        float v = (combA[t] + combB[t]) * invD_sh;
        wsrow[b*NH + t] = v;
        xcat_h[(size_t)b*KI0 + NF + t] = __float2half_rn(v);
    }
}

// ---------------------------------------------------------------------------
// GRU input-half via MFMA + gate combine. grid = 128 blocks x 256 threads.
// Block = (jg = blk>>2: 16 j's) x (bq = blk&3: 16 batches).
// Waves 0..2: gate g's 16x16 MFMA tile -> gis LDS. All 256 threads combine.
__global__ __launch_bounds__(256) void k_gru(
    const __half* __restrict__ Wi,
    const float* __restrict__ bi, const float* __restrict__ bh,
    const __half* __restrict__ xh, int K,     // [64][K] fp16
    const float* __restrict__ ghbL,           // [3*512][64] Wh . hold
    const float* __restrict__ hold,           // [64][512] fp32
    float* __restrict__ hnew,                 // [64][512] fp32 (may == hold)
    __half* __restrict__ hnewh)               // [64][512] fp16
{
    int blk = blockIdx.x, t = threadIdx.x;
    int w = t >> 6, lane = t & 63;
    int mr = lane & 15, kq = lane >> 4;
    int jg = blk >> 2, bq = blk & 3;
    int j0 = jg*16, b0 = bq*16;
    __shared__ float gis[3][16][17];          // [gate][j_local][b_local]

    if (w < 3) {
        int gate = w;
        const __half* arow = Wi + (size_t)(gate*NH + j0 + mr)*K;
        const __half* brow = xh + (size_t)(b0 + mr)*K;
        float4_t acc = {0.f,0.f,0.f,0.f};
        #pragma unroll 4
        for (int kb = 0; kb < K; kb += 32) {
            half8_t a = *(const half8_t*)(arow + kb + kq*8);
            half8_t b = *(const half8_t*)(brow + kb + kq*8);
            acc = __builtin_amdgcn_mfma_f32_16x16x32_f16(a, b, acc, 0, 0, 0);
        }
        #pragma unroll
        for (int r = 0; r < 4; ++r) gis[gate][kq*4 + r][mr] = acc[r];
    }
    __syncthreads();

    // combine: t = (j_local<<4) | b_local
    int jl = t >> 4, bl = t & 15;
    int j = j0 + jl, b = b0 + bl;
    float S0 = gis[0][jl][bl], S1 = gis[1][jl][bl], S2 = gis[2][jl][bl];
    float ghr = ghbL[(size_t)(0*NH + j)*NB + b];
    float ghz = ghbL[(size_t)(1*NH + j)*NB + b];
    float ghn = ghbL[(size_t)(2*NH + j)*NB + b];
    float r = fast_sig(S0 + ghr + bi[j] + bh[j]);
    float z = fast_sig(S1 + ghz + bi[NH + j] + bh[NH + j]);
    float n = fast_tanh(S2 + bi[2*NH + j] + r*(ghn + bh[2*NH + j]));
    float hp = hold[(size_t)b*NH + j];
    float hv = (1.f - z)*n + z*hp;
    hnew[(size_t)b*NH + j] = hv;
    hnewh[(size_t)b*NH + j] = __float2half_rn(hv);
}

// ---------------------------------------------------------------------------
extern "C" void kernel_launch(void* const* d_in, const int* in_sizes, int n_in,
                              void* d_out, int out_size, void* d_ws, size_t ws_size,
                              hipStream_t stream) {
    const float* inputs = (const float*)d_in[0];
    const float* hidden = (const float*)d_in[1];
    const float* enc    = (const float*)d_in[2];
    const int*   tgt    = (const int*)d_in[3];
    const float* Wattn  = (const float*)d_in[4];
    const float* battn  = (const float*)d_in[5];
    const float* vattn  = (const float*)d_in[6];
    const float* Wi0    = (const float*)d_in[7];
    const float* Wh0    = (const float*)d_in[8];
    const float* bi0    = (const float*)d_in[9];
    const float* bh0    = (const float*)d_in[10];
    const float* Wi1    = (const float*)d_in[11];
    const float* Wh1    = (const float*)d_in[12];
    const float* bi1    = (const float*)d_in[13];
    const float* bh1    = (const float*)d_in[14];
    const float* Wout   = (const float*)d_in[15];
    const float* bout   = (const float*)d_in[16];
    float* out = (float*)d_out;

    // Workspace (~15.1 MiB)
    float* h0row  = (float*)d_ws;             // [64][512]
    float* h1row  = h0row + NB*NH;            // [64][512]
    float* wsrow  = h1row + NB*NH;            // [64][512]
    float* currow = wsrow + NB*NH;            // [64][32]
    float* ghb    = currow + NB*NF;           // [2][3*512][64]
    __half* Wi0h  = (__half*)(ghb + 2*3*NH*NB);  // 1536 x 544
    __half* Wh0h  = Wi0h + 1536*KI0;          // 1536 x 512
    __half* Wi1h  = Wh0h + 1536*NH;           // 1536 x 512
    __half* Wh1h  = Wi1h + 1536*NH;           // 1536 x 512
    __half* Wouth = Wh1h + 1536*NH;           // 4 x 1056
    __half* WahT  = Wouth + 4*1056;           // [512 k][512 g]
    __half* WaeH  = WahT + NH*NH;             // [512 g][512 k]
    __half* h0h   = WaeH + NH*NH;             // [64][512]
    __half* h1h   = h0h + NB*NH;              // [64][512]
    __half* xcat_h= h1h + NB*NH;              // [64][544]
    __half* encph = xcat_h + NB*KI0;          // [6144][512]

    const int prep_n = 1536*KI0 + 3*1536*NH + 4*1056 + 2*NH*NH + NB*NH + NB*NF;
    k_prep<<<(prep_n + 255)/256, 256, 0, stream>>>(
        Wi0, Wh0, Wi1, Wh1, Wout, Wattn, hidden, inputs,
        Wi0h, Wh0h, Wi1h, Wh1h, Wouth, WahT, WaeH,
        h0row, h1row, h0h, h1h, currow, xcat_h);
    k_encproj<<<768, 256, 0, stream>>>(enc, WaeH, encph);

    for (int s = 0; s < NDEC; ++s) {
        k_step<<<NB + 48, 1024, 0, stream>>>(
            inputs, tgt, WahT, battn, vattn, Wouth, bout, encph, enc,
            Wh0h, Wh1h, h0h, h1h, h1row,
            wsrow, currow, xcat_h, ghb, out, s, 1);
        k_gru<<<128, 256, 0, stream>>>(Wi0h, bi0, bh0,
                                       xcat_h, KI0,
                                       ghb,
                                       h0row, h0row, h0h);
        k_gru<<<128, 256, 0, stream>>>(Wi1h, bi1, bh1,
                                       h0h, NH,
                                       ghb + 3*NH*NB,
                                       h1row, h1row, h1h);
    }
    // Final out(11) projection only; h1row holds h1(12)
    k_step<<<NB, 1024, 0, stream>>>(
        inputs, tgt, WahT, battn, vattn, Wouth, bout, encph, enc,
        Wh0h, Wh1h, h0h, h1h, h1row,
        wsrow, currow, xcat_h, ghb, out, NDEC, 0);
}

// Round 4
// 596.688 us; speedup vs baseline: 3.1424x; 1.1631x over previous
//
#include <hip/hip_runtime.h>
#include <hip/hip_fp16.h>

// Problem constants
#define NB   64     // batch
#define NDEC 12     // decoder steps
#define NF   32     // input features
#define NH   512    // hidden
#define NE   96     // encoder length
#define NT   4      // output dim
#define KI0  (NF + NH)   // 544 = K of layer-0 input GEMM
#define KOUT (2*NH + NF) // 1056 = K of out-proj GEMM

typedef _Float16 half8_t __attribute__((ext_vector_type(8)));
typedef float   float4_t __attribute__((ext_vector_type(4)));

__device__ __forceinline__ float fast_tanh(float x) {
    x = fminf(fmaxf(x, -15.f), 15.f);
    float e = __expf(2.f * x);
    return (e - 1.f) / (e + 1.f);
}
__device__ __forceinline__ float fast_sig(float x) {
    return 1.f / (1.f + __expf(-x));
}

// ---------------------------------------------------------------------------
// One-time: fp32->fp16 weight converts + state init.
__global__ __launch_bounds__(256) void k_prep(
    const float* __restrict__ Wi0, const float* __restrict__ Wh0,
    const float* __restrict__ Wi1, const float* __restrict__ Wh1,
    const float* __restrict__ Wout, const float* __restrict__ Wattn,
    const float* __restrict__ hidden, const float* __restrict__ inputs,
    __half* __restrict__ Wi0h, __half* __restrict__ Wh0h,
    __half* __restrict__ Wi1h, __half* __restrict__ Wh1h,
    __half* __restrict__ Wouth, __half* __restrict__ WahH,
    __half* __restrict__ WaeH,
    float* __restrict__ h0row, float* __restrict__ h1row,
    __half* __restrict__ h0h, __half* __restrict__ h1h,
    __half* __restrict__ xcat_h)
{
    int i = blockIdx.x*256 + threadIdx.x;
    const int n0 = 1536*KI0, n1 = 1536*512, n4 = 4*KOUT, n5 = 512*512;
    if (i < n0) { Wi0h[i] = __float2half_rn(Wi0[i]); return; }  i -= n0;
    if (i < n1) { Wh0h[i] = __float2half_rn(Wh0[i]); return; }  i -= n1;
    if (i < n1) { Wi1h[i] = __float2half_rn(Wi1[i]); return; }  i -= n1;
    if (i < n1) { Wh1h[i] = __float2half_rn(Wh1[i]); return; }  i -= n1;
    if (i < n4) { Wouth[i] = __float2half_rn(Wout[i]); return; } i -= n4;
    if (i < n5) {                                     // WahH[g][k] = Wattn[g][k]
        int g = i >> 9, k = i & 511;
        WahH[i] = __float2half_rn(Wattn[(size_t)g*1024 + k]);
        return;
    }
    i -= n5;
    if (i < n5) {                                     // WaeH[g][k] = Wattn[g][512+k]
        int g = i >> 9, k = i & 511;
        WaeH[i] = __float2half_rn(Wattn[(size_t)g*1024 + 512 + k]);
        return;
    }
    i -= n5;
    if (i < NB*NH) {                                  // state init (row-major)
        int b = i >> 9, k = i & 511;
        float v0 = hidden[b*NH + k];
        float v1 = hidden[NB*NH + b*NH + k];
        h0row[b*NH + k] = v0;  h0h[b*NH + k] = __float2half_rn(v0);
        h1row[b*NH + k] = v1;  h1h[b*NH + k] = __float2half_rn(v1);
        return;
    }
    i -= NB*NH;
    if (i < NB*NF) {                                  // cur(0)
        int b = i >> 5, k = i & 31;
        xcat_h[(size_t)b*KI0 + k] = __float2half_rn(inputs[b*NDEC*NF + k]);
    }
}

// ---------------------------------------------------------------------------
// enc_proj via MFMA f16: encp[be][g] = sum_k enc[be][k] * WaeH[g][k].
// Verified fragment layout: A[m=lane&15][k=(lane>>4)*8+i], B[n=lane&15][k...],
// D[row=(lane>>4)*4+r][col=lane&15].
__global__ __launch_bounds__(256) void k_encproj(const float* __restrict__ enc,
                                                 const __half* __restrict__ WaeH,
                                                 __half* __restrict__ encph) {
    int x = blockIdx.x;                 // 768 = 96 (m-tiles) x 8 (n-tiles)
    int by = x >> 3, bx = x & 7;
    int t = threadIdx.x, w = t >> 6, lane = t & 63;
    int mr = lane & 15, kq = lane >> 4;          // kq in 0..3
    int m = by*64 + w*16 + mr;
    const float* arow = enc + (size_t)m*NH;
    float4_t acc[4] = {{0.f,0.f,0.f,0.f},{0.f,0.f,0.f,0.f},
                       {0.f,0.f,0.f,0.f},{0.f,0.f,0.f,0.f}};
    for (int kb = 0; kb < NH; kb += 32) {
        int k = kb + kq*8;
        float4 a0 = *(const float4*)(arow + k);
        float4 a1 = *(const float4*)(arow + k + 4);
        half8_t a;
        a[0] = (_Float16)a0.x; a[1] = (_Float16)a0.y;
        a[2] = (_Float16)a0.z; a[3] = (_Float16)a0.w;
        a[4] = (_Float16)a1.x; a[5] = (_Float16)a1.y;
        a[6] = (_Float16)a1.z; a[7] = (_Float16)a1.w;
        #pragma unroll
        for (int j = 0; j < 4; ++j) {
            int n = bx*64 + j*16 + mr;
            half8_t b = *(const half8_t*)(WaeH + (size_t)n*NH + k);
            acc[j] = __builtin_amdgcn_mfma_f32_16x16x32_f16(a, b, acc[j], 0, 0, 0);
        }
    }
    #pragma unroll
    for (int j = 0; j < 4; ++j) {
        int col = bx*64 + j*16 + mr;
        #pragma unroll
        for (int r = 0; r < 4; ++r) {
            int row = by*64 + w*16 + kq*4 + r;
            encph[(size_t)row*NH + col] = __float2half_rn(acc[j][r]);
        }
    }
}

// ---------------------------------------------------------------------------
// Step-start GEMM kernel. All operands ready at step start.
//  blocks 0..223 (att_on): wave-tiles wid = blk*4+w
//    wid <  128 : att[g][b] = Wa_h @ h1^T + battn     (32 rowtiles x 4 bq)
//    wid >= 128 : ghb[layer][row][b] = Wh @ h^T       (192 rowtiles x 4 bq)
//  block 224 (or block 0 when !att_on): out-proj GEMM (M=4, K=1056, N=64),
//    writes out(s-1) and cur(s) into xcat_h.
__global__ __launch_bounds__(256) void k_gemA(
    const float* __restrict__ inputs, const int* __restrict__ tgt,
    const __half* __restrict__ WahH, const float* __restrict__ battn,
    const __half* __restrict__ Wouth, const float* __restrict__ bout,
    const __half* __restrict__ Wh0h, const __half* __restrict__ Wh1h,
    const __half* __restrict__ h0h, const __half* __restrict__ h1h,
    __half* __restrict__ xcat_h,
    float* __restrict__ attc,          // [512 g][64 b]  (battn included)
    float* __restrict__ ghb,           // [2][3*512][64]
    float* __restrict__ out,
    int s, int att_on)
{
    int blk = blockIdx.x, t = threadIdx.x;
    int w = t >> 6, lane = t & 63;
    int mr = lane & 15, kq = lane >> 4;
    int gA = att_on ? 224 : 0;

    if (blk < gA) {
        int wid = blk*4 + w;
        if (wid < 128) {
            // ---------------- att GEMM ----------------
            int rt = wid >> 2, bq = wid & 3;
            const __half* arow = WahH + (size_t)(rt*16 + mr)*NH;
            const __half* brow = h1h + (size_t)(bq*16 + mr)*NH;
            float4_t acc = {0.f,0.f,0.f,0.f};
            #pragma unroll 4
            for (int kb = 0; kb < NH; kb += 32) {
                half8_t a = *(const half8_t*)(arow + kb + kq*8);
                half8_t b = *(const half8_t*)(brow + kb + kq*8);
                acc = __builtin_amdgcn_mfma_f32_16x16x32_f16(a, b, acc, 0, 0, 0);
            }
            float* dst = attc + (size_t)(rt*16)*NB;
            #pragma unroll
            for (int r = 0; r < 4; ++r) {
                int grow = kq*4 + r;
                dst[(size_t)grow*NB + bq*16 + mr] = acc[r] + battn[rt*16 + grow];
            }
        } else {
            // ---------------- ghb GEMMs ----------------
            int gw = wid - 128;
            int rt = gw >> 2, bq = gw & 3;
            int layer = (rt >= 96) ? 1 : 0;
            int rloc = (rt - layer*96) * 16;
            const __half* Wh = layer ? Wh1h : Wh0h;
            const __half* Xh = layer ? h1h : h0h;
            const __half* arow = Wh + (size_t)(rloc + mr)*NH;
            const __half* brow = Xh + (size_t)(bq*16 + mr)*NH;
            float4_t acc = {0.f,0.f,0.f,0.f};
            #pragma unroll 4
            for (int kb = 0; kb < NH; kb += 32) {
                half8_t a = *(const half8_t*)(arow + kb + kq*8);
                half8_t b = *(const half8_t*)(brow + kb + kq*8);
                acc = __builtin_amdgcn_mfma_f32_16x16x32_f16(a, b, acc, 0, 0, 0);
            }
            float* gdst = ghb + ((size_t)layer*3*NH + rloc)*NB;
            #pragma unroll
            for (int r = 0; r < 4; ++r) {
                gdst[(size_t)(kq*4 + r)*NB + bq*16 + mr] = acc[r];
            }
        }
        return;
    }

    // ---------------- out-proj GEMM (block gA) ----------------
    if (s == 0) return;
    int bq = w;                         // 4 waves = 4 batch-quarters
    int b = bq*16 + mr;                 // this lane's batch column
    const __half* h1b = h1h + (size_t)b*NH;
    const __half* xcb = xcat_h + (size_t)b*KI0;     // [cur(s-1) | ws(s-1)]
    int ar = (mr < 4) ? mr : 3;         // clamp: rows 4..15 produce unused garbage
    const __half* arow = Wouth + (size_t)ar*KOUT;
    float4_t acc = {0.f,0.f,0.f,0.f};
    for (int kb = 0; kb < KOUT; kb += 32) {
        int k = kb + kq*8;
        half8_t a = *(const half8_t*)(arow + k);
        const __half* bp = (k < NH)   ? (h1b + k)
                         : (k < 2*NH) ? (xcb + NF + (k - NH))
                                      : (xcb + (k - 2*NH));
        half8_t bb = *(const half8_t*)bp;
        acc = __builtin_amdgcn_mfma_f32_16x16x32_f16(a, bb, acc, 0, 0, 0);
    }
    // D rows 0..3 (outputs) live in kq==0 lanes (lanes 0..15), col = mr.
    // Broadcast each b's 4 outputs to all lanes handling that b.
    float o0 = __shfl(acc[0], mr) + bout[0];
    float o1 = __shfl(acc[1], mr) + bout[1];
    float o2 = __shfl(acc[2], mr) + bout[2];
    float o3 = __shfl(acc[3], mr) + bout[3];
    if (kq == 0) {
        *(float4*)(out + (size_t)b*(NDEC*NT) + (s-1)*NT) = make_float4(o0,o1,o2,o3);
    }
    if (s < NDEC) {
        int t0 = tgt[0], t1 = tgt[1], t2 = tgt[2], t3 = tgt[3];
        const float* ip = inputs + (size_t)b*(NDEC*NF) + (s-1)*NF;
        half8_t hv;
        #pragma unroll
        for (int i = 0; i < 8; ++i) {
            int f = kq*8 + i;
            float v = ip[f];
            v = (f == t0) ? o0 : (f == t1) ? o1 : (f == t2) ? o2 : (f == t3) ? o3 : v;
            hv[i] = (_Float16)__float2half_rn(v);
        }
        *(half8_t*)(xcat_h + (size_t)b*KI0 + kq*8) = hv;
    }
}

// ---------------------------------------------------------------------------
// Per-batch softmax/ws kernel. grid = 64 x 1024.
__global__ __launch_bounds__(1024) void k_soft(
    const float* __restrict__ vattn,
    const float* __restrict__ attc,    // [512 g][64 b], battn included
    const __half* __restrict__ encph, const float* __restrict__ enc,
    __half* __restrict__ xcat_h)
{
    int b = blockIdx.x, t = threadIdx.x;
    int lane = t & 63, widx = t >> 6;
    __shared__ float vs[NH], atts[NH];
    __shared__ float pes[NE], combA[NH], combB[NH];
    __shared__ float invD_sh;

    if (t < NH) { vs[t] = vattn[t]; atts[t] = attc[(size_t)t*NB + b]; }
    __syncthreads();

    // scores -> exp (no max-subtract: |score| small)
    {
        float ar[8], vr[8];
        #pragma unroll
        for (int i = 0; i < 8; ++i) { ar[i] = atts[lane*8 + i]; vr[i] = vs[lane*8 + i]; }
        for (int it = 0; it < 6; ++it) {
            int e = widx + it*16;
            const __half* ep = encph + ((size_t)(b*NE + e))*NH + lane*8;
            uint4 u = *(const uint4*)ep;
            __half2 p0 = *(__half2*)&u.x, p1 = *(__half2*)&u.y;
            __half2 p2 = *(__half2*)&u.z, p3 = *(__half2*)&u.w;
            float2 f0 = __half22float2(p0), f1 = __half22float2(p1);
            float2 f2 = __half22float2(p2), f3 = __half22float2(p3);
            float sacc;
            sacc  = fast_tanh(f0.x + ar[0]) * vr[0];
            sacc += fast_tanh(f0.y + ar[1]) * vr[1];
            sacc += fast_tanh(f1.x + ar[2]) * vr[2];
            sacc += fast_tanh(f1.y + ar[3]) * vr[3];
            sacc += fast_tanh(f2.x + ar[4]) * vr[4];
            sacc += fast_tanh(f2.y + ar[5]) * vr[5];
            sacc += fast_tanh(f3.x + ar[6]) * vr[6];
            sacc += fast_tanh(f3.y + ar[7]) * vr[7];
            #pragma unroll
            for (int off = 32; off; off >>= 1) sacc += __shfl_down(sacc, off);
            if (lane == 0) pes[e] = __expf(sacc);
        }
    }
    __syncthreads();

    if (t < 64) {
        float v = pes[t] + ((t < 32) ? pes[64 + t] : 0.f);
        #pragma unroll
        for (int off = 32; off; off >>= 1) v += __shfl_down(v, off);
        if (t == 0) invD_sh = 1.f / v;
    }
    __syncthreads();

    // ws[k] = sum_e p[e] * enc[b,e,k]  (coalesced over k)
    {
        int k = t & 511, half = t >> 9;
        const float* eb = enc + ((size_t)b*NE + half*48)*NH + k;
        float acc = 0.f;
        #pragma unroll 4
        for (int e = 0; e < 48; ++e) acc += pes[half*48 + e] * eb[(size_t)e*NH];
        if (half == 0) combA[k] = acc; else combB[k] = acc;
    }
    __syncthreads();
    if (t < NH) {
        float v = (combA[t] + combB[t]) * invD_sh;
        xcat_h[(size_t)b*KI0 + NF + t] = __float2half_rn(v);
    }
}

// ---------------------------------------------------------------------------
// GRU input-half via MFMA + gate combine. grid = 128 blocks x 256 threads.
// Block = (jg = blk>>2: 16 j's) x (bq = blk&3: 16 batches).
__global__ __launch_bounds__(256) void k_gru(
    const __half* __restrict__ Wi,
    const float* __restrict__ bi, const float* __restrict__ bh,
    const __half* __restrict__ xh, int K,     // [64][K] fp16
    const float* __restrict__ ghbL,           // [3*512][64] Wh . hold
    const float* __restrict__ hold,           // [64][512] fp32
    float* __restrict__ hnew,                 // [64][512] fp32 (may == hold)
    __half* __restrict__ hnewh)               // [64][512] fp16
{
    int blk = blockIdx.x, t = threadIdx.x;
    int w = t >> 6, lane = t & 63;
    int mr = lane & 15, kq = lane >> 4;
    int jg = blk >> 2, bq = blk & 3;
    int j0 = jg*16, b0 = bq*16;
    __shared__ float gis[3][16][17];          // [gate][j_local][b_local]

    if (w < 3) {
        int gate = w;
        const __half* arow = Wi + (size_t)(gate*NH + j0 + mr)*K;
        const __half* brow = xh + (size_t)(b0 + mr)*K;
        float4_t acc = {0.f,0.f,0.f,0.f};
        #pragma unroll 4
        for (int kb = 0; kb < K; kb += 32) {
            half8_t a = *(const half8_t*)(arow + kb + kq*8);
            half8_t b = *(const half8_t*)(brow + kb + kq*8);
            acc = __builtin_amdgcn_mfma_f32_16x16x32_f16(a, b, acc, 0, 0, 0);
        }
        #pragma unroll
        for (int r = 0; r < 4; ++r) gis[gate][kq*4 + r][mr] = acc[r];
    }
    __syncthreads();

    // combine: t = (j_local<<4) | b_local
    int jl = t >> 4, bl = t & 15;
    int j = j0 + jl, b = b0 + bl;
    float S0 = gis[0][jl][bl], S1 = gis[1][jl][bl], S2 = gis[2][jl][bl];
    float ghr = ghbL[(size_t)(0*NH + j)*NB + b];
    float ghz = ghbL[(size_t)(1*NH + j)*NB + b];
    float ghn = ghbL[(size_t)(2*NH + j)*NB + b];
    float r = fast_sig(S0 + ghr + bi[j] + bh[j]);
    float z = fast_sig(S1 + ghz + bi[NH + j] + bh[NH + j]);
    float n = fast_tanh(S2 + bi[2*NH + j] + r*(ghn + bh[2*NH + j]));
    float hp = hold[(size_t)b*NH + j];
    float hv = (1.f - z)*n + z*hp;
    hnew[(size_t)b*NH + j] = hv;
    hnewh[(size_t)b*NH + j] = __float2half_rn(hv);
}

// ---------------------------------------------------------------------------
extern "C" void kernel_launch(void* const* d_in, const int* in_sizes, int n_in,
                              void* d_out, int out_size, void* d_ws, size_t ws_size,
                              hipStream_t stream) {
    const float* inputs = (const float*)d_in[0];
    const float* hidden = (const float*)d_in[1];
    const float* enc    = (const float*)d_in[2];
    const int*   tgt    = (const int*)d_in[3];
    const float* Wattn  = (const float*)d_in[4];
    const float* battn  = (const float*)d_in[5];
    const float* vattn  = (const float*)d_in[6];
    const float* Wi0    = (const float*)d_in[7];
    const float* Wh0    = (const float*)d_in[8];
    const float* bi0    = (const float*)d_in[9];
    const float* bh0    = (const float*)d_in[10];
    const float* Wi1    = (const float*)d_in[11];
    const float* Wh1    = (const float*)d_in[12];
    const float* bi1    = (const float*)d_in[13];
    const float* bh1    = (const float*)d_in[14];
    const float* Wout   = (const float*)d_in[15];
    const float* bout   = (const float*)d_in[16];
    float* out = (float*)d_out;

    // Workspace (~15.1 MiB)
    float* h0row  = (float*)d_ws;             // [64][512]
    float* h1row  = h0row + NB*NH;            // [64][512]
    float* ghb    = h1row + NB*NH;            // [2][3*512][64]
    float* attc   = ghb + 2*3*NH*NB;          // [512][64]
    __half* Wi0h  = (__half*)(attc + NH*NB);  // 1536 x 544
    __half* Wh0h  = Wi0h + 1536*KI0;          // 1536 x 512
    __half* Wi1h  = Wh0h + 1536*NH;           // 1536 x 512
    __half* Wh1h  = Wi1h + 1536*NH;           // 1536 x 512
    __half* Wouth = Wh1h + 1536*NH;           // 4 x 1056
    __half* WahH  = Wouth + 4*KOUT;           // [512 g][512 k]
    __half* WaeH  = WahH + NH*NH;             // [512 g][512 k]
    __half* h0h   = WaeH + NH*NH;             // [64][512]
    __half* h1h   = h0h + NB*NH;              // [64][512]
    __half* xcat_h= h1h + NB*NH;              // [64][544]
    __half* encph = xcat_h + NB*KI0;          // [6144][512]

    const int prep_n = 1536*KI0 + 3*1536*NH + 4*KOUT + 2*NH*NH + NB*NH + NB*NF;
    k_prep<<<(prep_n + 255)/256, 256, 0, stream>>>(
        Wi0, Wh0, Wi1, Wh1, Wout, Wattn, hidden, inputs,
        Wi0h, Wh0h, Wi1h, Wh1h, Wouth, WahH, WaeH,
        h0row, h1row, h0h, h1h, xcat_h);
    k_encproj<<<768, 256, 0, stream>>>(enc, WaeH, encph);

    for (int s = 0; s < NDEC; ++s) {
        k_gemA<<<(s == 0) ? 224 : 225, 256, 0, stream>>>(
            inputs, tgt, WahH, battn, Wouth, bout, Wh0h, Wh1h,
            h0h, h1h, xcat_h, attc, ghb, out, s, 1);
        k_soft<<<NB, 1024, 0, stream>>>(vattn, attc, encph, enc, xcat_h);
        k_gru<<<128, 256, 0, stream>>>(Wi0h, bi0, bh0,
                                       xcat_h, KI0,
                                       ghb,
                                       h0row, h0row, h0h);
        k_gru<<<128, 256, 0, stream>>>(Wi1h, bi1, bh1,
                                       h0h, NH,
                                       ghb + 3*NH*NB,
                                       h1row, h1row, h1h);
    }
    // Final: out(11) only
    k_gemA<<<1, 256, 0, stream>>>(
        inputs, tgt, WahH, battn, Wouth, bout, Wh0h, Wh1h,
        h0h, h1h, xcat_h, attc, ghb, out, NDEC, 0);
}